// Round 1
// baseline (5611.300 us; speedup 1.0000x reference)
//
#include <hip/hip_runtime.h>

#define D 32

// ---------------------------------------------------------------------------
// zero-fill (float4 stores)
// ---------------------------------------------------------------------------
__global__ __launch_bounds__(256) void zero_f32(float* __restrict__ p, long n4) {
    long i = (long)blockIdx.x * blockDim.x + threadIdx.x;
    long stride = (long)gridDim.x * blockDim.x;
    float4 z = make_float4(0.f, 0.f, 0.f, 0.f);
    for (long k = i; k < n4; k += stride) {
        ((float4*)p)[k] = z;
    }
}

// ---------------------------------------------------------------------------
// one direction of mean-aggregation (sum part): for each edge e,
//   sums[scatter_idx[e]] += src_feat[gather_idx[e]]   (32 floats)
//   deg [scatter_idx[e]] += 1
// 8 lanes per edge, float4 per lane.
// ---------------------------------------------------------------------------
__global__ __launch_bounds__(256) void scatter_dir(
        const float* __restrict__ src_feat,
        const int*   __restrict__ gather_idx,
        const int*   __restrict__ scatter_idx,
        float* __restrict__ sums,
        float* __restrict__ deg,
        int E) {
    long tid    = (long)blockIdx.x * blockDim.x + threadIdx.x;
    int  lane8  = (int)(tid & 7);
    long e      = tid >> 3;
    long stride = ((long)gridDim.x * blockDim.x) >> 3;
    for (; e < E; e += stride) {
        int s = gather_idx[e];
        int d = scatter_idx[e];
        float4 v = ((const float4*)(src_feat + (long)s * D))[lane8];
        float* dst = sums + (long)d * D + lane8 * 4;
        atomicAdd(dst + 0, v.x);
        atomicAdd(dst + 1, v.y);
        atomicAdd(dst + 2, v.z);
        atomicAdd(dst + 3, v.w);
        if (lane8 == 0) atomicAdd(&deg[d], 1.0f);
    }
}

// ---------------------------------------------------------------------------
// out[row] = embed[row] @ Wself + (out[row]/max(deg,1)) @ Wneigh + b
// (out holds the neighbor sums on entry; overwritten in place)
// 32 lanes per row; W's staged in LDS; shuffle-broadcast matvec.
// ---------------------------------------------------------------------------
__global__ __launch_bounds__(256) void sage_out(
        const float* __restrict__ embed,
        float*       __restrict__ out,
        const float* __restrict__ deg,
        const float* __restrict__ Wself,
        const float* __restrict__ Wneigh,
        const float* __restrict__ bias,
        int N) {
    __shared__ float sWs[D * D];
    __shared__ float sWn[D * D];
    __shared__ float sb[D];
    for (int i = threadIdx.x; i < D * D; i += blockDim.x) {
        sWs[i] = Wself[i];
        sWn[i] = Wneigh[i];
    }
    if (threadIdx.x < D) sb[threadIdx.x] = bias[threadIdx.x];
    __syncthreads();

    int  lane    = threadIdx.x & 31;
    long group   = ((long)blockIdx.x * blockDim.x + threadIdx.x) >> 5;
    long ngroups = ((long)gridDim.x * blockDim.x) >> 5;

    for (long row = group; row < N; row += ngroups) {
        float e  = embed[row * D + lane];
        float s  = out[row * D + lane];
        float dg = deg[row];
        float m  = s / fmaxf(dg, 1.0f);
        float acc = sb[lane];
#pragma unroll
        for (int k = 0; k < D; ++k) {
            float ek = __shfl(e, k, 32);
            float mk = __shfl(m, k, 32);
            acc += ek * sWs[k * D + lane] + mk * sWn[k * D + lane];
        }
        out[row * D + lane] = acc;
    }
}

// ---------------------------------------------------------------------------
extern "C" void kernel_launch(void* const* d_in, const int* in_sizes, int n_in,
                              void* d_out, int out_size, void* d_ws, size_t ws_size,
                              hipStream_t stream) {
    const float* user_embed = (const float*)d_in[0];
    const float* item_embed = (const float*)d_in[1];
    const float* W_self     = (const float*)d_in[2];
    const float* W_neigh    = (const float*)d_in[3];
    const float* bias       = (const float*)d_in[4];
    const int*   edge_src   = (const int*)d_in[5];
    const int*   edge_dst   = (const int*)d_in[6];

    const int NU = in_sizes[0] / D;
    const int NI = in_sizes[1] / D;
    const int E  = in_sizes[5];

    float* user_out = (float*)d_out;             // [NU*D] — sums, then final
    float* item_out = user_out + (long)NU * D;   // [NI*D]
    float* deg_user = (float*)d_ws;              // [NU]
    float* deg_item = deg_user + NU;             // [NI]

    // 1) zero accumulators (d_out used as the sum buffer) and degrees
    long n_out4 = ((long)(NU + NI) * D) / 4;
    zero_f32<<<4096, 256, 0, stream>>>(user_out, n_out4);
    long n_deg4 = ((long)(NU + NI)) / 4;
    zero_f32<<<512, 256, 0, stream>>>(deg_user, n_deg4);

    // 2) scatter-sum both directions (phase-split for L3 locality)
    long threads_needed = (long)E * 8;
    int  sblocks = (int)((threads_needed + 255) / 256);
    // user -> item aggregation
    scatter_dir<<<sblocks, 256, 0, stream>>>(user_embed, edge_src, edge_dst,
                                             item_out, deg_item, E);
    // item -> user aggregation
    scatter_dir<<<sblocks, 256, 0, stream>>>(item_embed, edge_dst, edge_src,
                                             user_out, deg_user, E);

    // 3) finalize: out = embed@Wself + mean@Wneigh + b   (in place over sums)
    int ublocks = (int)(((long)NU * 32 + 255) / 256);
    int iblocks = (int)(((long)NI * 32 + 255) / 256);
    sage_out<<<ublocks, 256, 0, stream>>>(user_embed, user_out, deg_user,
                                          W_self, W_neigh, bias, NU);
    sage_out<<<iblocks, 256, 0, stream>>>(item_embed, item_out, deg_item,
                                          W_self, W_neigh, bias, NI);
}

// Round 2
// 3422.131 us; speedup vs baseline: 1.6397x; 1.6397x over previous
//
#include <hip/hip_runtime.h>

#define D 32
#define SCAN_TPB 256
#define SCAN_CHUNK 2048   // SCAN_TPB * 8 elements per scan block

// ---------------------------------------------------------------------------
__global__ __launch_bounds__(256) void zero_i32(int* __restrict__ p, int n) {
    int i = blockIdx.x * blockDim.x + threadIdx.x;
    int stride = gridDim.x * blockDim.x;
    for (; i < n; i += stride) p[i] = 0;
}

// ---------------------------------------------------------------------------
// degree histogram over the combined row space: user rows [0,NU), item rows
// [NU, NU+NI). Each edge (s,d) increments deg[s] and deg[NU+d].
// ---------------------------------------------------------------------------
__global__ __launch_bounds__(256) void histogram(
        const int* __restrict__ src, const int* __restrict__ dst,
        int* __restrict__ deg, int NU, int E) {
    int i = blockIdx.x * blockDim.x + threadIdx.x;
    int stride = gridDim.x * blockDim.x;
    for (; i < E; i += stride) {
        atomicAdd(&deg[src[i]], 1);
        atomicAdd(&deg[NU + dst[i]], 1);
    }
}

// ---------------------------------------------------------------------------
// scan pass 1: per-block sums of SCAN_CHUNK elements
// ---------------------------------------------------------------------------
__global__ __launch_bounds__(SCAN_TPB) void scan_block_sums(
        const int* __restrict__ deg, int* __restrict__ partials, int n) {
    __shared__ int sd[SCAN_TPB];
    long base = (long)blockIdx.x * SCAN_CHUNK;
    int sum = 0;
    for (int i = threadIdx.x; i < SCAN_CHUNK; i += SCAN_TPB) {
        long g = base + i;
        if (g < n) sum += deg[g];
    }
    sd[threadIdx.x] = sum;
    __syncthreads();
    for (int off = SCAN_TPB / 2; off > 0; off >>= 1) {
        if (threadIdx.x < off) sd[threadIdx.x] += sd[threadIdx.x + off];
        __syncthreads();
    }
    if (threadIdx.x == 0) partials[blockIdx.x] = sd[0];
}

// ---------------------------------------------------------------------------
// scan pass 2: exclusive scan of the (<=1024) block partials, one block
// ---------------------------------------------------------------------------
__global__ __launch_bounds__(1024) void scan_top(int* __restrict__ partials, int np) {
    __shared__ int s[1024];
    int t = threadIdx.x;
    s[t] = (t < np) ? partials[t] : 0;
    __syncthreads();
    for (int off = 1; off < 1024; off <<= 1) {
        int v = (t >= off) ? s[t - off] : 0;
        __syncthreads();
        s[t] += v;
        __syncthreads();
    }
    if (t < np) partials[t] = (t == 0) ? 0 : s[t - 1];
}

// ---------------------------------------------------------------------------
// scan pass 3: rebuild local exclusive scan + block offset; write offs and a
// second copy (cursor) for the counting-sort fill. Thread t owns 8
// consecutive elements. Also writes the grand total at offs[n].
// ---------------------------------------------------------------------------
__global__ __launch_bounds__(SCAN_TPB) void scan_final(
        const int* __restrict__ deg, const int* __restrict__ partials,
        int* __restrict__ offs, int* __restrict__ cursor, int n) {
    __shared__ int sd[SCAN_TPB];
    int t = threadIdx.x;
    long base = (long)blockIdx.x * SCAN_CHUNK + (long)t * 8;
    int x[8], pre[8];
    int sum = 0;
#pragma unroll
    for (int j = 0; j < 8; ++j) {
        long g = base + j;
        x[j] = (g < n) ? deg[g] : 0;
        pre[j] = sum;
        sum += x[j];
    }
    sd[t] = sum;
    __syncthreads();
    for (int off = 1; off < SCAN_TPB; off <<= 1) {
        int v = (t >= off) ? sd[t - off] : 0;
        __syncthreads();
        sd[t] += v;
        __syncthreads();
    }
    int thread_prefix = (t == 0) ? 0 : sd[t - 1];
    int blockoff = partials[blockIdx.x];
#pragma unroll
    for (int j = 0; j < 8; ++j) {
        long g = base + j;
        if (g < n) {
            int o = blockoff + thread_prefix + pre[j];
            offs[g] = o;
            cursor[g] = o;
            if (g == n - 1) offs[n] = o + x[j];
        }
    }
}

// ---------------------------------------------------------------------------
// counting-sort fill: user row s gets neighbor item index d; item row NU+d
// gets neighbor user index s.
// ---------------------------------------------------------------------------
__global__ __launch_bounds__(256) void fill_csr(
        const int* __restrict__ src, const int* __restrict__ dst,
        int* __restrict__ cursor, int* __restrict__ csr, int NU, int E) {
    int i = blockIdx.x * blockDim.x + threadIdx.x;
    int stride = gridDim.x * blockDim.x;
    for (; i < E; i += stride) {
        int s = src[i];
        int d = dst[i];
        int p1 = atomicAdd(&cursor[s], 1);
        csr[p1] = d;
        int p2 = atomicAdd(&cursor[NU + d], 1);
        csr[p2] = s;
    }
}

// ---------------------------------------------------------------------------
// fused aggregate + SAGE transform. One 32-lane group per row of the
// combined row space. Gathers neighbor rows (coalesced 128B reads), means,
// then out = self@Wself + mean@Wneigh + b via LDS-staged W + shuffle matvec.
// ---------------------------------------------------------------------------
__global__ __launch_bounds__(256) void sage_fused(
        const float* __restrict__ user_embed, const float* __restrict__ item_embed,
        const int* __restrict__ offs, const int* __restrict__ csr,
        const float* __restrict__ Wself, const float* __restrict__ Wneigh,
        const float* __restrict__ bias,
        float* __restrict__ user_out, float* __restrict__ item_out,
        int NU, int N2) {
    __shared__ float sWs[D * D];
    __shared__ float sWn[D * D];
    __shared__ float sb[D];
    for (int i = threadIdx.x; i < D * D; i += blockDim.x) {
        sWs[i] = Wself[i];
        sWn[i] = Wneigh[i];
    }
    if (threadIdx.x < D) sb[threadIdx.x] = bias[threadIdx.x];
    __syncthreads();

    int lane = threadIdx.x & 31;
    long row = ((long)blockIdx.x * blockDim.x + threadIdx.x) >> 5;
    long nrows = ((long)gridDim.x * blockDim.x) >> 5;

    for (; row < N2; row += nrows) {
        const float* self;
        const float* nsrc;
        float* out;
        if (row < NU) {
            self = user_embed + row * D;
            nsrc = item_embed;
            out  = user_out + row * D;
        } else {
            long r = row - NU;
            self = item_embed + r * D;
            nsrc = user_embed;
            out  = item_out + r * D;
        }
        int o0 = offs[row];
        int o1 = offs[row + 1];
        float s = 0.f;
        for (int j = o0; j < o1; ++j) {
            int idx = csr[j];
            s += nsrc[(long)idx * D + lane];
        }
        float m = s / fmaxf((float)(o1 - o0), 1.0f);
        float e = self[lane];
        float acc = sb[lane];
#pragma unroll
        for (int k = 0; k < D; ++k) {
            acc += __shfl(e, k, 32) * sWs[k * D + lane]
                 + __shfl(m, k, 32) * sWn[k * D + lane];
        }
        out[lane] = acc;
    }
}

// ---------------------------------------------------------------------------
extern "C" void kernel_launch(void* const* d_in, const int* in_sizes, int n_in,
                              void* d_out, int out_size, void* d_ws, size_t ws_size,
                              hipStream_t stream) {
    const float* user_embed = (const float*)d_in[0];
    const float* item_embed = (const float*)d_in[1];
    const float* W_self     = (const float*)d_in[2];
    const float* W_neigh    = (const float*)d_in[3];
    const float* bias       = (const float*)d_in[4];
    const int*   edge_src   = (const int*)d_in[5];
    const int*   edge_dst   = (const int*)d_in[6];

    const int NU = in_sizes[0] / D;
    const int NI = in_sizes[1] / D;
    const int E  = in_sizes[5];
    const int N2 = NU + NI;

    float* user_out = (float*)d_out;            // [NU*D]
    float* item_out = user_out + (long)NU * D;  // [NI*D]

    // workspace layout (ints): deg[N2] | offs[N2+1] | cursor[N2] | partials[1024] | csr[2E]
    int* deg      = (int*)d_ws;
    int* offs     = deg + N2;
    int* cursor   = offs + N2 + 1;
    int* partials = cursor + N2;
    int* csr      = partials + 1024;

    const int np = (N2 + SCAN_CHUNK - 1) / SCAN_CHUNK;  // 977 for 2M rows (<=1024)

    // 1) zero degrees
    zero_i32<<<2048, 256, 0, stream>>>(deg, N2);

    // 2) degree histogram (both directions in one pass)
    histogram<<<4096, 256, 0, stream>>>(edge_src, edge_dst, deg, NU, E);

    // 3) exclusive scan -> offs (and cursor copy)
    scan_block_sums<<<np, SCAN_TPB, 0, stream>>>(deg, partials, N2);
    scan_top<<<1, 1024, 0, stream>>>(partials, np);
    scan_final<<<np, SCAN_TPB, 0, stream>>>(deg, partials, offs, cursor, N2);

    // 4) counting-sort edge endpoints into combined CSR
    fill_csr<<<4096, 256, 0, stream>>>(edge_src, edge_dst, cursor, csr, NU, E);

    // 5) fused gather-mean + SAGE transform, one pass over all 2M rows
    int blocks = (int)(((long)N2 * 32 + 255) / 256);
    sage_fused<<<blocks, 256, 0, stream>>>(user_embed, item_embed, offs, csr,
                                           W_self, W_neigh, bias,
                                           user_out, item_out, NU, N2);
}

// Round 3
// 2629.656 us; speedup vs baseline: 2.1339x; 1.3014x over previous
//
#include <hip/hip_runtime.h>

#define D 32
#define SCAN_TPB 256
#define SCAN_CHUNK 2048   // SCAN_TPB * 8 elements per scan block

// ---------------------------------------------------------------------------
__global__ __launch_bounds__(256) void zero_i32(int* __restrict__ p, int n) {
    int i = blockIdx.x * blockDim.x + threadIdx.x;
    int stride = gridDim.x * blockDim.x;
    for (; i < n; i += stride) p[i] = 0;
}

// ---------------------------------------------------------------------------
// degree histogram over the combined row space: user rows [0,NU), item rows
// [NU, NU+NI). Each edge (s,d) increments deg[s] and deg[NU+d].
// ---------------------------------------------------------------------------
__global__ __launch_bounds__(256) void histogram(
        const int* __restrict__ src, const int* __restrict__ dst,
        int* __restrict__ deg, int NU, int E) {
    int i = blockIdx.x * blockDim.x + threadIdx.x;
    int stride = gridDim.x * blockDim.x;
    for (; i < E; i += stride) {
        atomicAdd(&deg[src[i]], 1);
        atomicAdd(&deg[NU + dst[i]], 1);
    }
}

// ---------------------------------------------------------------------------
// scan pass 1: per-block sums of SCAN_CHUNK elements
// ---------------------------------------------------------------------------
__global__ __launch_bounds__(SCAN_TPB) void scan_block_sums(
        const int* __restrict__ deg, int* __restrict__ partials, int n) {
    __shared__ int sd[SCAN_TPB];
    long base = (long)blockIdx.x * SCAN_CHUNK;
    int sum = 0;
    for (int i = threadIdx.x; i < SCAN_CHUNK; i += SCAN_TPB) {
        long g = base + i;
        if (g < n) sum += deg[g];
    }
    sd[threadIdx.x] = sum;
    __syncthreads();
    for (int off = SCAN_TPB / 2; off > 0; off >>= 1) {
        if (threadIdx.x < off) sd[threadIdx.x] += sd[threadIdx.x + off];
        __syncthreads();
    }
    if (threadIdx.x == 0) partials[blockIdx.x] = sd[0];
}

// ---------------------------------------------------------------------------
// scan pass 2: exclusive scan of the (<=1024) block partials, one block
// ---------------------------------------------------------------------------
__global__ __launch_bounds__(1024) void scan_top(int* __restrict__ partials, int np) {
    __shared__ int s[1024];
    int t = threadIdx.x;
    s[t] = (t < np) ? partials[t] : 0;
    __syncthreads();
    for (int off = 1; off < 1024; off <<= 1) {
        int v = (t >= off) ? s[t - off] : 0;
        __syncthreads();
        s[t] += v;
        __syncthreads();
    }
    if (t < np) partials[t] = (t == 0) ? 0 : s[t - 1];
}

// ---------------------------------------------------------------------------
// scan pass 3: rebuild local exclusive scan + block offset; write offs and a
// cursor copy for the counting-sort fill. Also writes grand total at offs[n].
// ---------------------------------------------------------------------------
__global__ __launch_bounds__(SCAN_TPB) void scan_final(
        const int* __restrict__ deg, const int* __restrict__ partials,
        int* __restrict__ offs, int* __restrict__ cursor, int n) {
    __shared__ int sd[SCAN_TPB];
    int t = threadIdx.x;
    long base = (long)blockIdx.x * SCAN_CHUNK + (long)t * 8;
    int x[8], pre[8];
    int sum = 0;
#pragma unroll
    for (int j = 0; j < 8; ++j) {
        long g = base + j;
        x[j] = (g < n) ? deg[g] : 0;
        pre[j] = sum;
        sum += x[j];
    }
    sd[t] = sum;
    __syncthreads();
    for (int off = 1; off < SCAN_TPB; off <<= 1) {
        int v = (t >= off) ? sd[t - off] : 0;
        __syncthreads();
        sd[t] += v;
        __syncthreads();
    }
    int thread_prefix = (t == 0) ? 0 : sd[t - 1];
    int blockoff = partials[blockIdx.x];
#pragma unroll
    for (int j = 0; j < 8; ++j) {
        long g = base + j;
        if (g < n) {
            int o = blockoff + thread_prefix + pre[j];
            offs[g] = o;
            cursor[g] = o;
            if (g == n - 1) offs[n] = o + x[j];
        }
    }
}

// ---------------------------------------------------------------------------
// counting-sort fill: user row s gets neighbor item index d; item row NU+d
// gets neighbor user index s.
// ---------------------------------------------------------------------------
__global__ __launch_bounds__(256) void fill_csr(
        const int* __restrict__ src, const int* __restrict__ dst,
        int* __restrict__ cursor, int* __restrict__ csr, int NU, int E) {
    int i = blockIdx.x * blockDim.x + threadIdx.x;
    int stride = gridDim.x * blockDim.x;
    for (; i < E; i += stride) {
        int s = src[i];
        int d = dst[i];
        int p1 = atomicAdd(&cursor[s], 1);
        csr[p1] = d;
        int p2 = atomicAdd(&cursor[NU + d], 1);
        csr[p2] = s;
    }
}

// ---------------------------------------------------------------------------
// one phase of fused aggregate + SAGE transform (dst rows gather from one
// source table, which stays L3-resident for the whole dispatch).
// One 32-lane group per row. csr indices batch-loaded (1 coalesced load per
// 32 neighbors), gathers issued in 8-wide independent batches (MLP).
// ---------------------------------------------------------------------------
__global__ __launch_bounds__(256, 8) void sage_phase(
        const float* __restrict__ self_embed,
        const float* __restrict__ nbr_embed,
        const int* __restrict__ offs,      // [N+1], pre-offset for this phase
        const int* __restrict__ csr,
        const float* __restrict__ Wself, const float* __restrict__ Wneigh,
        const float* __restrict__ bias,
        float* __restrict__ out, int N) {
    __shared__ float sWs[D * D];
    __shared__ float sWn[D * D];
    __shared__ float sb[D];
    for (int i = threadIdx.x; i < D * D; i += blockDim.x) {
        sWs[i] = Wself[i];
        sWn[i] = Wneigh[i];
    }
    if (threadIdx.x < D) sb[threadIdx.x] = bias[threadIdx.x];
    __syncthreads();

    int lane = threadIdx.x & 31;
    long g  = ((long)blockIdx.x * blockDim.x + threadIdx.x) >> 5;
    long ng = ((long)gridDim.x * blockDim.x) >> 5;

    for (long row = g; row < N; row += ng) {
        int o0 = offs[row];
        int o1 = offs[row + 1];
        int deg = o1 - o0;
        float s = 0.f;
        for (int j0 = o0; j0 < o1; j0 += 32) {
            int nb = o1 - j0;
            if (nb > 32) nb = 32;
            // batch-load up to 32 neighbor indices (coalesced; clamped dup tail)
            int idx = csr[j0 + (lane < nb ? lane : nb - 1)];
            for (int k = 0; k < nb; k += 8) {
                int kr = nb - k;  // >= 1
                float v[8];
#pragma unroll
                for (int u = 0; u < 8; ++u) {
                    int uu = u < kr ? u : kr - 1;       // clamp (dup loads are cache hits)
                    int bi = __shfl(idx, k + uu, 32);
                    v[u] = nbr_embed[(long)bi * D + lane];
                }
#pragma unroll
                for (int u = 0; u < 8; ++u) {
                    s += (u < kr) ? v[u] : 0.f;
                }
            }
        }
        float m = s / fmaxf((float)deg, 1.0f);
        float e = self_embed[row * D + lane];
        float acc = sb[lane];
#pragma unroll
        for (int k = 0; k < D; ++k) {
            acc += __shfl(e, k, 32) * sWs[k * D + lane]
                 + __shfl(m, k, 32) * sWn[k * D + lane];
        }
        out[row * D + lane] = acc;
    }
}

// ---------------------------------------------------------------------------
extern "C" void kernel_launch(void* const* d_in, const int* in_sizes, int n_in,
                              void* d_out, int out_size, void* d_ws, size_t ws_size,
                              hipStream_t stream) {
    const float* user_embed = (const float*)d_in[0];
    const float* item_embed = (const float*)d_in[1];
    const float* W_self     = (const float*)d_in[2];
    const float* W_neigh    = (const float*)d_in[3];
    const float* bias       = (const float*)d_in[4];
    const int*   edge_src   = (const int*)d_in[5];
    const int*   edge_dst   = (const int*)d_in[6];

    const int NU = in_sizes[0] / D;
    const int NI = in_sizes[1] / D;
    const int E  = in_sizes[5];
    const int N2 = NU + NI;

    float* user_out = (float*)d_out;            // [NU*D]
    float* item_out = user_out + (long)NU * D;  // [NI*D]

    // workspace (ints): deg[N2] | offs[N2+1] | cursor[N2] | partials[1024] | csr[2E]
    int* deg      = (int*)d_ws;
    int* offs     = deg + N2;
    int* cursor   = offs + N2 + 1;
    int* partials = cursor + N2;
    int* csr      = partials + 1024;

    const int np = (N2 + SCAN_CHUNK - 1) / SCAN_CHUNK;  // <= 1024

    // 1) zero degrees
    zero_i32<<<2048, 256, 0, stream>>>(deg, N2);

    // 2) degree histogram (both directions in one pass)
    histogram<<<4096, 256, 0, stream>>>(edge_src, edge_dst, deg, NU, E);

    // 3) exclusive scan -> offs (and cursor copy)
    scan_block_sums<<<np, SCAN_TPB, 0, stream>>>(deg, partials, N2);
    scan_top<<<1, 1024, 0, stream>>>(partials, np);
    scan_final<<<np, SCAN_TPB, 0, stream>>>(deg, partials, offs, cursor, N2);

    // 4) counting-sort edge endpoints into combined CSR
    fill_csr<<<4096, 256, 0, stream>>>(edge_src, edge_dst, cursor, csr, NU, E);

    // 5) fused gather-mean + SAGE transform, phase-split so each phase's
    //    gather table (128 MB) stays L3-resident
    sage_phase<<<2048, 256, 0, stream>>>(user_embed, item_embed, offs, csr,
                                         W_self, W_neigh, bias, user_out, NU);
    sage_phase<<<2048, 256, 0, stream>>>(item_embed, user_embed, offs + NU, csr,
                                         W_self, W_neigh, bias, item_out, NI);
}